// Round 1
// baseline (705.661 us; speedup 1.0000x reference)
//
#include <hip/hip_runtime.h>

#define N_LEVELS 8
#define F_DIM 8
#define N_PIX (12 * 128 * 128)      // 196608 rows allocated per level
#define PACKED_ROWS 262140          // sum_{l=0..7} 12*4^l
#define PACKED_BYTES ((size_t)PACKED_ROWS * F_DIM * 2)

using f32x4 = __attribute__((ext_vector_type(4))) float;
using u16x8 = __attribute__((ext_vector_type(8))) unsigned short;

__device__ __forceinline__ unsigned short f32_to_bf16_rne(float x) {
    unsigned u = __float_as_uint(x);
    return (unsigned short)((u + 0x7fffu + ((u >> 16) & 1u)) >> 16);
}

__device__ __forceinline__ float bf16_hi_to_f32(unsigned short h) {
    return __uint_as_float(((unsigned)h) << 16);
}

// ---- Pass 1: pack the touched rows of params into a compact bf16 table ----
// packed row offset for level l: 4*(4^l - 1); rows at level l: 12*4^l.
__global__ __launch_bounds__(256) void pack_params_bf16(
    const float* __restrict__ params, unsigned short* __restrict__ packed)
{
    int l = blockIdx.y;
    unsigned rows = 12u << (2 * l);
    unsigned r = blockIdx.x * 256 + threadIdx.x;
    if (r >= rows) return;
    const f32x4* src = (const f32x4*)(params + ((size_t)l * N_PIX + r) * F_DIM);
    f32x4 a = __builtin_nontemporal_load(src);
    f32x4 c = __builtin_nontemporal_load(src + 1);
    unsigned rowoff = ((1u << (2 * l)) - 1u) * 4u;
    u16x8 o;
    o[0] = f32_to_bf16_rne(a[0]); o[1] = f32_to_bf16_rne(a[1]);
    o[2] = f32_to_bf16_rne(a[2]); o[3] = f32_to_bf16_rne(a[3]);
    o[4] = f32_to_bf16_rne(c[0]); o[5] = f32_to_bf16_rne(c[1]);
    o[6] = f32_to_bf16_rne(c[2]); o[7] = f32_to_bf16_rne(c[3]);
    *(u16x8*)(packed + ((size_t)(rowoff + r) << 3)) = o;
}

// ---- Pass 2: main encoding. 4 threads per batch element, 2 levels each. ----
// Thread sub-index q handles levels {q, 7-q}: one tiny L1-hot table + one
// large scattered table per thread -> balanced lanes, and only 8 independent
// gathers per thread so ALL of them fit in registers and stay in flight
// (the round-1 kernel was MLP-starved: 48 VGPRs forced ~4 outstanding
// gathers per wave -> 95% vmcnt stall).
// Output is transposed through LDS so the final stores are coalesced 16B.
__global__ __launch_bounds__(256) void heal_enc_bf16_v2(
    const unsigned short* __restrict__ packed,
    const int*   __restrict__ pix,     // [8][4][batch]
    const float* __restrict__ wgt,     // [8][4][batch]
    float*       __restrict__ out,     // [batch][64], out[b][f*8+l]
    int batch)
{
    // 64 batch rows per block; pad 68 so staging writes are 2-way bank
    // aliased (free) : bank = (4*row + 8*f + l) % 32, distinct per lane pair.
    __shared__ float stage[64][68];

    const int tl = threadIdx.x;
    const int t  = blockIdx.x * 256 + tl;
    const int b  = t >> 2;
    const int q  = t & 3;              // sub-thread: levels {q, 7-q}
    const int rl = tl >> 2;            // local batch row 0..63

    if (b < batch) {
        const int lA = q;              // small level 0..3 (L1-hot table)
        const int lB = 7 - q;          // big   level 7..4 (L2 scatter)
        const size_t sb = (size_t)batch;
        const size_t baseA = (size_t)(lA * 4) * sb + (size_t)b;
        const size_t baseB = (size_t)(lB * 4) * sb + (size_t)b;

        // Issue all 16 streaming index/weight loads first (independent).
        int   ia[4], ib[4];
        float wa[4], wb[4];
#pragma unroll
        for (int n = 0; n < 4; ++n) {
            ia[n] = __builtin_nontemporal_load(pix + baseA + (size_t)n * sb);
            ib[n] = __builtin_nontemporal_load(pix + baseB + (size_t)n * sb);
        }
#pragma unroll
        for (int n = 0; n < 4; ++n) {
            wa[n] = __builtin_nontemporal_load(wgt + baseA + (size_t)n * sb);
            wb[n] = __builtin_nontemporal_load(wgt + baseB + (size_t)n * sb);
        }

        const unsigned roA = ((1u << (2 * lA)) - 1u) * 4u;
        const unsigned roB = ((1u << (2 * lB)) - 1u) * 4u;

        // All 8 gathers live in registers simultaneously (32 VGPRs).
        u16x8 ra[4], rb[4];
#pragma unroll
        for (int n = 0; n < 4; ++n)
            ra[n] = *(const u16x8*)(packed + ((size_t)(roA + (unsigned)ia[n]) << 3));
#pragma unroll
        for (int n = 0; n < 4; ++n)
            rb[n] = *(const u16x8*)(packed + ((size_t)(roB + (unsigned)ib[n]) << 3));

        float accA[8], accB[8];
#pragma unroll
        for (int f = 0; f < 8; ++f) { accA[f] = 0.f; accB[f] = 0.f; }
#pragma unroll
        for (int n = 0; n < 4; ++n) {
#pragma unroll
            for (int f = 0; f < 8; ++f) {
                accA[f] = fmaf(wa[n], bf16_hi_to_f32(ra[n][f]), accA[f]);
                accB[f] = fmaf(wb[n], bf16_hi_to_f32(rb[n][f]), accB[f]);
            }
        }

        // Stage: out element for (f, l) is f*8 + l.
#pragma unroll
        for (int f = 0; f < 8; ++f) {
            stage[rl][f * 8 + lA] = accA[f];
            stage[rl][f * 8 + lB] = accB[f];
        }
    }
    __syncthreads();

    // Cooperative coalesced write-out: thread owns 64B of one 256B out row.
    const int rr = tl >> 2;
    const int c  = tl & 3;
    const int bb = blockIdx.x * 64 + rr;
    if (bb < batch) {
        f32x4* o = (f32x4*)(out + (size_t)bb * (F_DIM * N_LEVELS) + c * 16);
#pragma unroll
        for (int k = 0; k < 4; ++k) {
            f32x4 v = *(const f32x4*)&stage[rr][c * 16 + k * 4];
            __builtin_nontemporal_store(v, o + k);
        }
    }
}

// ---- Fallback (ws too small): round-1 fp32 kernel ----
__global__ __launch_bounds__(256) void heal_enc_f32(
    const float* __restrict__ params,
    const int*   __restrict__ pix,
    const float* __restrict__ wgt,
    float*       __restrict__ out,
    int batch)
{
    int b = blockIdx.x * 256 + threadIdx.x;
    if (b >= batch) return;
    const size_t sb = (size_t)batch;
    float acc[64];
#pragma unroll
    for (int l = 0; l < N_LEVELS; ++l) {
        float4 r0 = make_float4(0.f, 0.f, 0.f, 0.f);
        float4 r1 = make_float4(0.f, 0.f, 0.f, 0.f);
#pragma unroll
        for (int n = 0; n < 4; ++n) {
            size_t off = (size_t)(l * 4 + n) * sb + (size_t)b;
            int   idx = pix[off];
            float w   = wgt[off];
            const float4* row =
                (const float4*)(params + ((size_t)l * N_PIX + (size_t)idx) * F_DIM);
            float4 p0 = row[0];
            float4 p1 = row[1];
            r0.x = fmaf(w, p0.x, r0.x); r0.y = fmaf(w, p0.y, r0.y);
            r0.z = fmaf(w, p0.z, r0.z); r0.w = fmaf(w, p0.w, r0.w);
            r1.x = fmaf(w, p1.x, r1.x); r1.y = fmaf(w, p1.y, r1.y);
            r1.z = fmaf(w, p1.z, r1.z); r1.w = fmaf(w, p1.w, r1.w);
        }
        acc[0*8+l] = r0.x; acc[1*8+l] = r0.y; acc[2*8+l] = r0.z; acc[3*8+l] = r0.w;
        acc[4*8+l] = r1.x; acc[5*8+l] = r1.y; acc[6*8+l] = r1.z; acc[7*8+l] = r1.w;
    }
    float4* o = (float4*)(out + (size_t)b * (F_DIM * N_LEVELS));
#pragma unroll
    for (int c = 0; c < 16; ++c)
        o[c] = make_float4(acc[4*c+0], acc[4*c+1], acc[4*c+2], acc[4*c+3]);
}

extern "C" void kernel_launch(void* const* d_in, const int* in_sizes, int n_in,
                              void* d_out, int out_size, void* d_ws, size_t ws_size,
                              hipStream_t stream)
{
    const float* params = (const float*)d_in[0];
    const int*   pix    = (const int*)d_in[1];
    const float* wgt    = (const float*)d_in[2];
    float*       out    = (float*)d_out;

    int batch = in_sizes[2] / (N_LEVELS * 4);

    if (ws_size >= PACKED_BYTES) {
        unsigned short* packed = (unsigned short*)d_ws;
        dim3 pgrid((N_PIX + 255) / 256, N_LEVELS);
        pack_params_bf16<<<pgrid, 256, 0, stream>>>(params, packed);
        int grid = (4 * batch + 255) / 256;
        heal_enc_bf16_v2<<<grid, 256, 0, stream>>>(packed, pix, wgt, out, batch);
    } else {
        int grid = (batch + 255) / 256;
        heal_enc_f32<<<grid, 256, 0, stream>>>(params, pix, wgt, out, batch);
    }
}

// Round 2
// 501.075 us; speedup vs baseline: 1.4083x; 1.4083x over previous
//
#include <hip/hip_runtime.h>

#define N_LEVELS 8
#define F_DIM 8
#define N_PIX (12 * 128 * 128)      // 196608 rows allocated per level
#define PACKED_ROWS 262140          // sum_{l=0..7} 12*4^l
#define PACKED_BYTES ((size_t)PACKED_ROWS * F_DIM * 2)

using f32x4 = __attribute__((ext_vector_type(4))) float;
using u16x8 = __attribute__((ext_vector_type(8))) unsigned short;

__device__ __forceinline__ unsigned short f32_to_bf16_rne(float x) {
    unsigned u = __float_as_uint(x);
    return (unsigned short)((u + 0x7fffu + ((u >> 16) & 1u)) >> 16);
}

__device__ __forceinline__ float bf16_hi_to_f32(unsigned short h) {
    return __uint_as_float(((unsigned)h) << 16);
}

// ---- Pass 1: pack the touched rows of params into a compact bf16 table ----
// packed row offset for level l: 4*(4^l - 1); rows at level l: 12*4^l.
__global__ __launch_bounds__(256) void pack_params_bf16(
    const float* __restrict__ params, unsigned short* __restrict__ packed)
{
    int l = blockIdx.y;
    unsigned rows = 12u << (2 * l);
    unsigned r = blockIdx.x * 256 + threadIdx.x;
    if (r >= rows) return;
    const f32x4* src = (const f32x4*)(params + ((size_t)l * N_PIX + r) * F_DIM);
    f32x4 a = __builtin_nontemporal_load(src);
    f32x4 c = __builtin_nontemporal_load(src + 1);
    unsigned rowoff = ((1u << (2 * l)) - 1u) * 4u;
    u16x8 o;
    o[0] = f32_to_bf16_rne(a[0]); o[1] = f32_to_bf16_rne(a[1]);
    o[2] = f32_to_bf16_rne(a[2]); o[3] = f32_to_bf16_rne(a[3]);
    o[4] = f32_to_bf16_rne(c[0]); o[5] = f32_to_bf16_rne(c[1]);
    o[6] = f32_to_bf16_rne(c[2]); o[7] = f32_to_bf16_rne(c[3]);
    *(u16x8*)(packed + ((size_t)(rowoff + r) << 3)) = o;
}

// ---- Pass 2: main encoding. 2 threads per batch element (4 levels each). ----
// v3: same compute structure as the 291us v1 (it was the fastest), but the
// output now goes through an LDS transpose so every wave store instruction
// writes 1KB CONTIGUOUS (full dirty lines). v1's strided 32B store chunks
// caused 1.74x write amplification (445MB vs 256MB logical) and the system
// is pinned at ~2.2 TB/s effective HBM throughput -> bytes are the cost.
// All 16 pix loads are hoisted ahead of the gathers (single vmcnt wait),
// and launch_bounds(256,4) gives a 128-VGPR budget (same 4 blocks/CU as
// v1's measured occupancy) so 8 gather rows can stay in flight per chunk.
__global__ __launch_bounds__(256, 4) void heal_enc_bf16_v3(
    const unsigned short* __restrict__ packed,
    const int*   __restrict__ pix,     // [8][4][batch]
    const float* __restrict__ wgt,     // [8][4][batch]
    float*       __restrict__ out,     // [batch][64], out[b][f*8+l]
    int batch)
{
    // 128 batch rows per block. Pad to 68 floats so row stride (272B) stays
    // 16B-aligned for f32x4 readback; write-side conflicts are mild and the
    // LDS phase is <<1% of kernel time.
    __shared__ float stage[128][68];

    const int tl = threadIdx.x;
    const int t  = blockIdx.x * 256 + tl;
    const int b  = t >> 1;
    const int h  = t & 1;              // half: levels h*4 .. h*4+3
    const int rl = tl >> 1;            // local batch row 0..127

    if (b < batch) {
        const size_t sb = (size_t)batch;

        float acc[32];
#pragma unroll
        for (int i = 0; i < 32; ++i) acc[i] = 0.f;

        // Hoist ALL index/weight stream loads (16+16, independent, one wait).
        int   idx[4][4];
        float w[4][4];
#pragma unroll
        for (int lr = 0; lr < 4; ++lr) {
            const int l = h * 4 + lr;
            const size_t base = (size_t)(l * 4) * sb + (size_t)b;
#pragma unroll
            for (int n = 0; n < 4; ++n) {
                idx[lr][n] = __builtin_nontemporal_load(pix + base + (size_t)n * sb);
                w[lr][n]   = __builtin_nontemporal_load(wgt + base + (size_t)n * sb);
            }
        }

        // Gathers in 2 chunks of 8 rows in flight (32 VGPRs of rows max,
        // stays under the 128-VGPR budget without spill).
#pragma unroll
        for (int c = 0; c < 2; ++c) {
            u16x8 row[2][4];
#pragma unroll
            for (int lr2 = 0; lr2 < 2; ++lr2) {
                const int lr = c * 2 + lr2;
                const int l  = h * 4 + lr;
                const unsigned ro = ((1u << (2 * l)) - 1u) * 4u;
#pragma unroll
                for (int n = 0; n < 4; ++n)
                    row[lr2][n] = *(const u16x8*)(
                        packed + ((size_t)(ro + (unsigned)idx[lr][n]) << 3));
            }
#pragma unroll
            for (int lr2 = 0; lr2 < 2; ++lr2) {
                const int lr = c * 2 + lr2;
#pragma unroll
                for (int n = 0; n < 4; ++n) {
#pragma unroll
                    for (int f = 0; f < 8; ++f)
                        acc[lr * 8 + f] =
                            fmaf(w[lr][n], bf16_hi_to_f32(row[lr2][n][f]),
                                 acc[lr * 8 + f]);
                }
            }
        }

        // Stage: out element for (f, l) is f*8 + l, l = h*4 + lr.
#pragma unroll
        for (int f = 0; f < 8; ++f) {
#pragma unroll
            for (int lr = 0; lr < 4; ++lr)
                stage[rl][f * 8 + h * 4 + lr] = acc[lr * 8 + f];
        }
    }
    __syncthreads();

    // Cooperative write-out: per store instruction a wave covers 1KB
    // contiguous (64 lanes x 16B) -> full dirty lines, no amplification.
    const int blockRow0 = blockIdx.x * 128;
#pragma unroll
    for (int k = 0; k < 8; ++k) {
        const int idx16 = k * 256 + tl;       // which 16B chunk of block tile
        const int row   = idx16 >> 4;         // 16 chunks per 256B out row
        const int chunk = idx16 & 15;
        const int bb    = blockRow0 + row;
        if (bb < batch) {
            f32x4 v = *(const f32x4*)&stage[row][chunk * 4];
            __builtin_nontemporal_store(
                v, (f32x4*)(out + (size_t)bb * (F_DIM * N_LEVELS)) + chunk);
        }
    }
}

// ---- Fallback (ws too small): round-1 fp32 kernel ----
__global__ __launch_bounds__(256) void heal_enc_f32(
    const float* __restrict__ params,
    const int*   __restrict__ pix,
    const float* __restrict__ wgt,
    float*       __restrict__ out,
    int batch)
{
    int b = blockIdx.x * 256 + threadIdx.x;
    if (b >= batch) return;
    const size_t sb = (size_t)batch;
    float acc[64];
#pragma unroll
    for (int l = 0; l < N_LEVELS; ++l) {
        float4 r0 = make_float4(0.f, 0.f, 0.f, 0.f);
        float4 r1 = make_float4(0.f, 0.f, 0.f, 0.f);
#pragma unroll
        for (int n = 0; n < 4; ++n) {
            size_t off = (size_t)(l * 4 + n) * sb + (size_t)b;
            int   idx = pix[off];
            float w   = wgt[off];
            const float4* row =
                (const float4*)(params + ((size_t)l * N_PIX + (size_t)idx) * F_DIM);
            float4 p0 = row[0];
            float4 p1 = row[1];
            r0.x = fmaf(w, p0.x, r0.x); r0.y = fmaf(w, p0.y, r0.y);
            r0.z = fmaf(w, p0.z, r0.z); r0.w = fmaf(w, p0.w, r0.w);
            r1.x = fmaf(w, p1.x, r1.x); r1.y = fmaf(w, p1.y, r1.y);
            r1.z = fmaf(w, p1.z, r1.z); r1.w = fmaf(w, p1.w, r1.w);
        }
        acc[0*8+l] = r0.x; acc[1*8+l] = r0.y; acc[2*8+l] = r0.z; acc[3*8+l] = r0.w;
        acc[4*8+l] = r1.x; acc[5*8+l] = r1.y; acc[6*8+l] = r1.z; acc[7*8+l] = r1.w;
    }
    float4* o = (float4*)(out + (size_t)b * (F_DIM * N_LEVELS));
#pragma unroll
    for (int c = 0; c < 16; ++c)
        o[c] = make_float4(acc[4*c+0], acc[4*c+1], acc[4*c+2], acc[4*c+3]);
}

extern "C" void kernel_launch(void* const* d_in, const int* in_sizes, int n_in,
                              void* d_out, int out_size, void* d_ws, size_t ws_size,
                              hipStream_t stream)
{
    const float* params = (const float*)d_in[0];
    const int*   pix    = (const int*)d_in[1];
    const float* wgt    = (const float*)d_in[2];
    float*       out    = (float*)d_out;

    int batch = in_sizes[2] / (N_LEVELS * 4);

    if (ws_size >= PACKED_BYTES) {
        unsigned short* packed = (unsigned short*)d_ws;
        dim3 pgrid((N_PIX + 255) / 256, N_LEVELS);
        pack_params_bf16<<<pgrid, 256, 0, stream>>>(params, packed);
        int grid = (2 * batch + 255) / 256;
        heal_enc_bf16_v3<<<grid, 256, 0, stream>>>(packed, pix, wgt, out, batch);
    } else {
        int grid = (batch + 255) / 256;
        heal_enc_f32<<<grid, 256, 0, stream>>>(params, pix, wgt, out, batch);
    }
}

// Round 3
// 485.752 us; speedup vs baseline: 1.4527x; 1.0315x over previous
//
#include <hip/hip_runtime.h>

#define N_LEVELS 8
#define F_DIM 8
#define N_PIX (12 * 128 * 128)      // 196608 rows allocated per level
#define PACKED_ROWS 262140          // sum_{l=0..7} 12*4^l
#define PACKED_BYTES ((size_t)PACKED_ROWS * F_DIM * 2)
#define SMALL_ROWS 1020             // rows of levels 0..3 = 12+48+192+768

using f32x4 = __attribute__((ext_vector_type(4))) float;
using u16x8 = __attribute__((ext_vector_type(8))) unsigned short;

__device__ __forceinline__ unsigned short f32_to_bf16_rne(float x) {
    unsigned u = __float_as_uint(x);
    return (unsigned short)((u + 0x7fffu + ((u >> 16) & 1u)) >> 16);
}

__device__ __forceinline__ float bf16_hi_to_f32(unsigned short h) {
    return __uint_as_float(((unsigned)h) << 16);
}

// ---- Pass 1: pack the touched rows of params into a compact bf16 table ----
// packed row offset for level l: 4*(4^l - 1); rows at level l: 12*4^l.
__global__ __launch_bounds__(256) void pack_params_bf16(
    const float* __restrict__ params, unsigned short* __restrict__ packed)
{
    int l = blockIdx.y;
    unsigned rows = 12u << (2 * l);
    unsigned r = blockIdx.x * 256 + threadIdx.x;
    if (r >= rows) return;
    const f32x4* src = (const f32x4*)(params + ((size_t)l * N_PIX + r) * F_DIM);
    f32x4 a = __builtin_nontemporal_load(src);
    f32x4 c = __builtin_nontemporal_load(src + 1);
    unsigned rowoff = ((1u << (2 * l)) - 1u) * 4u;
    u16x8 o;
    o[0] = f32_to_bf16_rne(a[0]); o[1] = f32_to_bf16_rne(a[1]);
    o[2] = f32_to_bf16_rne(a[2]); o[3] = f32_to_bf16_rne(a[3]);
    o[4] = f32_to_bf16_rne(c[0]); o[5] = f32_to_bf16_rne(c[1]);
    o[6] = f32_to_bf16_rne(c[2]); o[7] = f32_to_bf16_rne(c[3]);
    *(u16x8*)(packed + ((size_t)(rowoff + r) << 3)) = o;
}

// ---- Pass 2: main encoding, v4. ----
// 2 threads per batch element, but split WAVE-UNIFORM by level half:
//   waves 0-1 (h=0): levels 0-3 -> gathers served from an LDS copy of the
//                    16.3KB small-level table prefix (DS pipe),
//   waves 2-3 (h=1): levels 4-7 -> global scattered gathers (vmem pipe).
// This halves global gather transactions (32M -> 16M) and runs the other
// half on the concurrent DS pipe. Streaming pix/wgt loads are fully
// coalesced (64 consecutive b per wave). Output goes through the XOR-
// swizzled LDS stage so wave stores are 1KB contiguous full dirty lines.
__global__ __launch_bounds__(256, 3) void heal_enc_bf16_v4(
    const unsigned short* __restrict__ packed,
    const int*   __restrict__ pix,     // [8][4][batch]
    const float* __restrict__ wgt,     // [8][4][batch]
    float*       __restrict__ out,     // [batch][64], out[b][f*8+l]
    int batch)
{
    __shared__ float stage[128][68];   // 34816 B, XOR-swizzled 16B groups
    __shared__ u16x8 table[SMALL_ROWS];// 16320 B, levels 0..3 packed prefix

    const int tl = threadIdx.x;

    // Cooperative table load: 1020 x 16B, coalesced, L2-hot across blocks.
#pragma unroll
    for (int i = 0; i < 4; ++i) {
        int r = i * 256 + tl;
        if (r < SMALL_ROWS)
            table[r] = *(const u16x8*)(packed + ((size_t)r << 3));
    }

    const int rl = tl & 127;           // local batch row 0..127
    const int h  = tl >> 7;            // 0: waves 0-1 (lvls 0-3), 1: waves 2-3
    const int b  = blockIdx.x * 128 + rl;

    __syncthreads();

    if (b < batch) {
        const size_t sb = (size_t)batch;

        // Hoist all 16+16 streaming loads (independent, coalesced 256B/wave).
        int   idx[4][4];
        float w[4][4];
#pragma unroll
        for (int lr = 0; lr < 4; ++lr) {
            const int l = h * 4 + lr;
            const size_t base = (size_t)(l * 4) * sb + (size_t)b;
#pragma unroll
            for (int n = 0; n < 4; ++n) {
                idx[lr][n] = __builtin_nontemporal_load(pix + base + (size_t)n * sb);
                w[lr][n]   = __builtin_nontemporal_load(wgt + base + (size_t)n * sb);
            }
        }

        float acc[32];
#pragma unroll
        for (int i = 0; i < 32; ++i) acc[i] = 0.f;

        if (h == 0) {
            // Levels 0..3 from LDS. Read all 16 rows, then FMA.
            u16x8 row[4][4];
#pragma unroll
            for (int lr = 0; lr < 4; ++lr) {
                const unsigned ro = ((1u << (2 * lr)) - 1u) * 4u; // 0,12,60,252
#pragma unroll
                for (int n = 0; n < 4; ++n)
                    row[lr][n] = table[ro + (unsigned)idx[lr][n]];
            }
#pragma unroll
            for (int lr = 0; lr < 4; ++lr)
#pragma unroll
                for (int n = 0; n < 4; ++n)
#pragma unroll
                    for (int f = 0; f < 8; ++f)
                        acc[lr * 8 + f] = fmaf(
                            w[lr][n], bf16_hi_to_f32(row[lr][n][f]),
                            acc[lr * 8 + f]);
        } else {
            // Levels 4..7 from global, 2 chunks of 8 rows in flight.
#pragma unroll
            for (int c = 0; c < 2; ++c) {
                u16x8 row[2][4];
#pragma unroll
                for (int lr2 = 0; lr2 < 2; ++lr2) {
                    const int lr = c * 2 + lr2;
                    const int l  = 4 + lr;
                    const unsigned ro = ((1u << (2 * l)) - 1u) * 4u;
#pragma unroll
                    for (int n = 0; n < 4; ++n)
                        row[lr2][n] = *(const u16x8*)(
                            packed + ((size_t)(ro + (unsigned)idx[lr][n]) << 3));
                }
#pragma unroll
                for (int lr2 = 0; lr2 < 2; ++lr2) {
                    const int lr = c * 2 + lr2;
#pragma unroll
                    for (int n = 0; n < 4; ++n)
#pragma unroll
                        for (int f = 0; f < 8; ++f)
                            acc[lr * 8 + f] = fmaf(
                                w[lr][n], bf16_hi_to_f32(row[lr2][n][f]),
                                acc[lr * 8 + f]);
                }
            }
        }

        // Stage (vectorized + XOR swizzle): logical 16B group G = 2f+h holds
        // levels h*4..h*4+3 of feature f; stored at group G ^ (rl&7).
#pragma unroll
        for (int f = 0; f < 8; ++f) {
            f32x4 v = { acc[0 * 8 + f], acc[1 * 8 + f],
                        acc[2 * 8 + f], acc[3 * 8 + f] };
            *(f32x4*)&stage[rl][4 * ((2 * f + h) ^ (rl & 7))] = v;
        }
    }
    __syncthreads();

    // Cooperative write-out: per store instruction a wave covers 1KB
    // contiguous (64 lanes x 16B) -> full dirty lines, no amplification.
    const int blockRow0 = blockIdx.x * 128;
#pragma unroll
    for (int k = 0; k < 8; ++k) {
        const int idx16 = k * 256 + tl;       // which 16B chunk of block tile
        const int row   = idx16 >> 4;         // 16 chunks per 256B out row
        const int chunk = idx16 & 15;
        const int bb    = blockRow0 + row;
        if (bb < batch) {
            f32x4 v = *(const f32x4*)&stage[row][4 * (chunk ^ (row & 7))];
            __builtin_nontemporal_store(
                v, (f32x4*)(out + (size_t)bb * (F_DIM * N_LEVELS)) + chunk);
        }
    }
}

// ---- Fallback (ws too small): round-1 fp32 kernel ----
__global__ __launch_bounds__(256) void heal_enc_f32(
    const float* __restrict__ params,
    const int*   __restrict__ pix,
    const float* __restrict__ wgt,
    float*       __restrict__ out,
    int batch)
{
    int b = blockIdx.x * 256 + threadIdx.x;
    if (b >= batch) return;
    const size_t sb = (size_t)batch;
    float acc[64];
#pragma unroll
    for (int l = 0; l < N_LEVELS; ++l) {
        float4 r0 = make_float4(0.f, 0.f, 0.f, 0.f);
        float4 r1 = make_float4(0.f, 0.f, 0.f, 0.f);
#pragma unroll
        for (int n = 0; n < 4; ++n) {
            size_t off = (size_t)(l * 4 + n) * sb + (size_t)b;
            int   idx = pix[off];
            float w   = wgt[off];
            const float4* row =
                (const float4*)(params + ((size_t)l * N_PIX + (size_t)idx) * F_DIM);
            float4 p0 = row[0];
            float4 p1 = row[1];
            r0.x = fmaf(w, p0.x, r0.x); r0.y = fmaf(w, p0.y, r0.y);
            r0.z = fmaf(w, p0.z, r0.z); r0.w = fmaf(w, p0.w, r0.w);
            r1.x = fmaf(w, p1.x, r1.x); r1.y = fmaf(w, p1.y, r1.y);
            r1.z = fmaf(w, p1.z, r1.z); r1.w = fmaf(w, p1.w, r1.w);
        }
        acc[0*8+l] = r0.x; acc[1*8+l] = r0.y; acc[2*8+l] = r0.z; acc[3*8+l] = r0.w;
        acc[4*8+l] = r1.x; acc[5*8+l] = r1.y; acc[6*8+l] = r1.z; acc[7*8+l] = r1.w;
    }
    float4* o = (float4*)(out + (size_t)b * (F_DIM * N_LEVELS));
#pragma unroll
    for (int c = 0; c < 16; ++c)
        o[c] = make_float4(acc[4*c+0], acc[4*c+1], acc[4*c+2], acc[4*c+3]);
}

extern "C" void kernel_launch(void* const* d_in, const int* in_sizes, int n_in,
                              void* d_out, int out_size, void* d_ws, size_t ws_size,
                              hipStream_t stream)
{
    const float* params = (const float*)d_in[0];
    const int*   pix    = (const int*)d_in[1];
    const float* wgt    = (const float*)d_in[2];
    float*       out    = (float*)d_out;

    int batch = in_sizes[2] / (N_LEVELS * 4);

    if (ws_size >= PACKED_BYTES) {
        unsigned short* packed = (unsigned short*)d_ws;
        dim3 pgrid((N_PIX + 255) / 256, N_LEVELS);
        pack_params_bf16<<<pgrid, 256, 0, stream>>>(params, packed);
        int grid = (batch + 127) / 128;
        heal_enc_bf16_v4<<<grid, 256, 0, stream>>>(packed, pix, wgt, out, batch);
    } else {
        int grid = (batch + 255) / 256;
        heal_enc_f32<<<grid, 256, 0, stream>>>(params, pix, wgt, out, batch);
    }
}